// Round 3
// baseline (378.073 us; speedup 1.0000x reference)
//
#include <hip/hip_runtime.h>

// ODE_23390391894829: batched RK4 integration of constant-curvature rod.
// Reference quirks replicated:
//  - actions[:,3:6] are NEVER used (reference loop re-reads segment 0 at n=0).
//  - lengths for BOTH segments come from l = L0 + actions[:,0].
//  - segment 2 continues the same trajectory (autonomous ODE, constant u).
// Output: (2T, B, 14) fp32, out[t] = traj[min(t,L)] per segment.
//
// R4->R5: store-pipeline depth fix. R2 (barrier) and R4 (wave-local) timed
// identically (~130us vs 61us write roofline) because BOTH drain stores once
// per row: R2 via the barrier's vmcnt(0), R4 via register reuse -- the 3.5
// readback quads are recycled every row, so the compiler must wait vmcnt~0
// before the next row's ds_read overwrites pending store-data VGPRs.
// Fix: process rows in PAIRS. Stage 2 rows into a contiguous 7168B per-wave
// region, ONE lgkmcnt(0), read back into 7 DISTINCT f32x4 quads (2 rows =
// 448 f32x4 = exactly 7 per lane, no tail), 7 nt stores, then two full RK4
// steps (~700 cyc) elapse before the quads are reused -> stores stay in
// flight. Pair regions double-buffered so pair p+1's ds_writes can't race
// pair p's ds_reads (drained by the intervening lgkmcnt(0)).

#define C_L0 0.05f
#define C_D  0.0075f
#define C_DS 0.005f
#define NB   256   // batch elements per block == block size (4 waves)
#define NW   (NB / 64)

typedef float f32x4 __attribute__((ext_vector_type(4)));
typedef float f32x2 __attribute__((ext_vector_type(2)));

__device__ __forceinline__ void ode_f(const float* __restrict__ y, float ux, float uy,
                                      float* __restrict__ d) {
    d[0] = y[5];
    d[1] = y[8];
    d[2] = y[11];
#pragma unroll
    for (int i = 0; i < 3; ++i) {
        float Ri0 = y[3 + 3 * i + 0];
        float Ri1 = y[3 + 3 * i + 1];
        float Ri2 = y[3 + 3 * i + 2];
        d[3 + 3 * i + 0] = -uy * Ri2;
        d[3 + 3 * i + 1] =  ux * Ri2;
        d[3 + 3 * i + 2] =  uy * Ri0 - ux * Ri1;
    }
}

__device__ __forceinline__ void rk4_step(float* __restrict__ y, float ux, float uy) {
    const float h = C_DS;
    float k1[12], k2[12], k3[12], k4[12], t[12];
    ode_f(y, ux, uy, k1);
#pragma unroll
    for (int i = 0; i < 12; ++i) t[i] = y[i] + (0.5f * h) * k1[i];
    ode_f(t, ux, uy, k2);
#pragma unroll
    for (int i = 0; i < 12; ++i) t[i] = y[i] + (0.5f * h) * k2[i];
    ode_f(t, ux, uy, k3);
#pragma unroll
    for (int i = 0; i < 12; ++i) t[i] = y[i] + h * k3[i];
    ode_f(t, ux, uy, k4);
    const float c = h / 6.0f;
#pragma unroll
    for (int i = 0; i < 12; ++i)
        y[i] = y[i] + c * (k1[i] + 2.0f * k2[i] + 2.0f * k3[i] + k4[i]);
}

__device__ __forceinline__ void stage_row(float* __restrict__ dstf,
                                          const float* __restrict__ y,
                                          float ux, float uy) {
    f32x2* dst = (f32x2*)dstf;
    dst[0] = (f32x2){y[0],  y[1]};
    dst[1] = (f32x2){y[2],  y[3]};
    dst[2] = (f32x2){y[4],  y[5]};
    dst[3] = (f32x2){y[6],  y[7]};
    dst[4] = (f32x2){y[8],  y[9]};
    dst[5] = (f32x2){y[10], y[11]};
    dst[6] = (f32x2){ux, uy};
}

__global__ void __launch_bounds__(NB)
ode_kernel(const float* __restrict__ act, float* __restrict__ out, int B, int T) {
    // [region][wave][row-of-pair][896 floats]: per-wave pair region is a
    // CONTIGUOUS 7168 B (2 rows x 64 lanes x 14 floats), double-buffered.
    // Total 2*4*2*896*4 = 57344 B -> 2 blocks/CU (8 waves/CU; fill hits
    // full write BW at ~3 waves/CU, so occupancy is not the constraint).
    __shared__ float lds[2][NW][2][896];

    const int tid  = threadIdx.x;
    const int lane = tid & 63;
    const int wv   = tid >> 6;
    const int b    = blockIdx.x * NB + tid;   // B % NB == 0

    const float a0 = act[b * 6 + 0];
    const float a1 = act[b * 6 + 1];
    const float a2 = act[b * 6 + 2];

    const float l  = C_L0 + a0;
    const float ld = l * C_D;
    const float ux = a2 / (-ld);
    const float uy = a1 / ld;
    const int   L  = (int)floorf(l / C_DS);

    float y[12];
    y[0] = 0.f; y[1] = 0.f; y[2] = 0.f;
    y[3] = 1.f; y[4] = 0.f; y[5] = 0.f;
    y[6] = 0.f; y[7] = 1.f; y[8] = 0.f;
    y[9] = 0.f; y[10] = 0.f; y[11] = 1.f;

    // Per-wave global base (row 0 chunk); each row chunk is 3584 B.
    f32x4* g = (f32x4*)(out + ((size_t)blockIdx.x * NB + (size_t)wv * 64) * 14);
    const size_t RS = (size_t)B * 14 / 4;   // f32x4s per (·, B, 14) row

    int region = 0;
    // 2T rows flattened: row r -> seg = r>=T, t = r % T (r < 2T).
    // Step happens when t in [1, L]; at the seg boundary t wraps to 0 (no
    // step -> row T repeats the masked end state, matching the reference).
    for (int p = 0; p < T; ++p) {
        const int r0 = 2 * p;
        const int r1 = 2 * p + 1;
        const int t0 = (r0 < T) ? r0 : r0 - T;
        const int t1 = (r1 < T) ? r1 : r1 - T;

        if (t0 >= 1 && t0 <= L) rk4_step(y, ux, uy);
        stage_row(&lds[region][wv][0][lane * 14], y, ux, uy);

        if (t1 >= 1 && t1 <= L) rk4_step(y, ux, uy);
        stage_row(&lds[region][wv][1][lane * 14], y, ux, uy);

        // Wave-local: drains this pair's ds_writes AND the previous pair's
        // ds_reads (so region reuse at p+1 is safe). No s_barrier, no vmcnt.
        asm volatile("s_waitcnt lgkmcnt(0)" ::: "memory");
        __builtin_amdgcn_sched_barrier(0);

        // Dense readback of the 7168 B pair region: 448 f32x4 = 7/lane,
        // into 7 DISTINCT quads so pending stores never block the next
        // pair's ds_reads with a vmcnt(0)-depth wait.
        const f32x4* s = (const f32x4*)&lds[region][wv][0][0];
        f32x4 q0 = s[lane];
        f32x4 q1 = s[lane +  64];
        f32x4 q2 = s[lane + 128];
        f32x4 q3 = s[lane + 192];   // k=192+lane: spans the row boundary
        f32x4 q4 = s[lane + 256];
        f32x4 q5 = s[lane + 320];
        f32x4 q6 = s[lane + 384];

        f32x4* g0 = g;        // row r0 chunk (224 f32x4)
        f32x4* g1 = g + RS;   // row r1 chunk
        __builtin_nontemporal_store(q0, &g0[lane]);
        __builtin_nontemporal_store(q1, &g0[lane + 64]);
        __builtin_nontemporal_store(q2, &g0[lane + 128]);
        // k = 192+lane: lanes 0-31 -> row0 tail [192..224), lanes 32-63 ->
        // row1 head [0..32). Two 512 B contiguous segments, one instr.
        f32x4* a3 = (lane < 32) ? (g0 + 192 + lane) : (g1 + (lane - 32));
        __builtin_nontemporal_store(q3, a3);
        __builtin_nontemporal_store(q4, &g1[lane +  32]);
        __builtin_nontemporal_store(q5, &g1[lane +  96]);
        __builtin_nontemporal_store(q6, &g1[lane + 160]);

        g += 2 * RS;
        region ^= 1;
    }
}

extern "C" void kernel_launch(void* const* d_in, const int* in_sizes, int n_in,
                              void* d_out, int out_size, void* d_ws, size_t ws_size,
                              hipStream_t stream) {
    const float* act = (const float*)d_in[0];
    float* out = (float*)d_out;
    int B = in_sizes[0] / 6;               // (B, 6) actions
    int T = out_size / (2 * 14 * B);       // output is (2T, B, 14)

    int blocks = B / NB;                   // B = 262144 -> 1024 blocks
    hipLaunchKernelGGL(ode_kernel, dim3(blocks), dim3(NB), 0, stream,
                       act, out, B, T);
}